// Round 7
// baseline (550.710 us; speedup 1.0000x reference)
//
#include <hip/hip_runtime.h>
#include <hip/hip_bf16.h>

#define N 4096
#define IND 256
#define OUTD 128
#define NEGV -9000000000000000.0f

// ---------------- Kernel A: wh = lstm_out @ W  (4096x256 @ 256x128) ----------------
__global__ __launch_bounds__(256) void wh_kernel(const float* __restrict__ x,
                                                 const float* __restrict__ W,
                                                 float* __restrict__ wh) {
    __shared__ float xs[8][IND];
    const int t = threadIdx.x;
    const int i0 = blockIdx.x * 8;
    const float4* src = (const float4*)(x + (size_t)i0 * IND);
    float4* dst = (float4*)&xs[0][0];
    dst[t] = src[t];
    dst[t + 256] = src[t + 256];
    __syncthreads();
    const int c = t & 127;
    const int rbase = (t >> 7) * 4;
    float acc[4] = {0.f, 0.f, 0.f, 0.f};
    #pragma unroll 4
    for (int k = 0; k < IND; k += 4) {
        const float w0 = W[(k + 0) * OUTD + c];
        const float w1 = W[(k + 1) * OUTD + c];
        const float w2 = W[(k + 2) * OUTD + c];
        const float w3 = W[(k + 3) * OUTD + c];
        #pragma unroll
        for (int r = 0; r < 4; ++r) {
            const float4 xv = *(const float4*)&xs[rbase + r][k];
            acc[r] = fmaf(xv.x, w0, acc[r]);
            acc[r] = fmaf(xv.y, w1, acc[r]);
            acc[r] = fmaf(xv.z, w2, acc[r]);
            acc[r] = fmaf(xv.w, w3, acc[r]);
        }
    }
    #pragma unroll
    for (int r = 0; r < 4; ++r)
        wh[(size_t)(i0 + rbase + r) * OUTD + c] = acc[r];
}

// ---------------- Kernel A2: s_i = wh @ a_i, s_j = wh @ a_j ----------------
__global__ __launch_bounds__(128) void sij_kernel(const float* __restrict__ wh,
                                                  const float* __restrict__ a,
                                                  float* __restrict__ s_i,
                                                  float* __restrict__ s_j) {
    const int i = blockIdx.x;
    const int c = threadIdx.x;
    float v = wh[(size_t)i * OUTD + c];
    float p = v * a[c];              // a_i = a[0:128]
    float q = v * a[OUTD + 5 + c];   // a_j = a[133:261]
    #pragma unroll
    for (int off = 32; off >= 1; off >>= 1) {
        p += __shfl_down(p, off);
        q += __shfl_down(q, off);
    }
    __shared__ float tmp[4];
    if ((c & 63) == 0) { tmp[c >> 6] = p; tmp[2 + (c >> 6)] = q; }
    __syncthreads();
    if (c == 0) { s_i[i] = tmp[0] + tmp[1]; s_j[i] = tmp[2] + tmp[3]; }
}

// ---------------- Kernel B: flash GAT with async LDS edge staging ----------------
// 512 blocks x 256 threads (4 waves). BI=8 rows, BJ=128 j, 32 subtiles.
// Edge tile (8 rows x 128 j x 5 f32 = 20 KB) staged via global_load_lds (16B,
// zero VGPR cost), double-buffered. Per subtile:
//   [1] issue async stage of st+1 -> E[b^1]   (stays in flight through PV)
//   [2] scores(st) from E[b] -> P[b], online softmax (wave w owns rows 2w,2w+1)
//   [3] lgkmcnt(0)-only barrier (P visible; stage NOT drained)
//   [4] PV(st): 8 cols x 8 rows per thread from P[b] + wh (L2-resident)
//   [5] __syncthreads (drains vmcnt -> E[b^1] ready for next scores)
// NO __launch_bounds__: rounds 3/5/6 showed every cap variant ((512,7)->36,
// (512,4)->64, (256,2)->128 VGPR) triggers massive scratch spills. Default =
// 512-VGPR budget; pressure here ~130 -> no spill. Spill sentinel: WRITE_SIZE.
#define BI 8
#define BJ 128
#define NSUB (N / BJ)        // 32
#define PSTR 132
#define EFLOATS (BI * BJ * 5)  // 5120 floats = 20 KB per buffer

#define FMA4(A, pv, wv)                  \
    A.x = fmaf(pv, wv.x, A.x);           \
    A.y = fmaf(pv, wv.y, A.y);           \
    A.z = fmaf(pv, wv.z, A.z);           \
    A.w = fmaf(pv, wv.w, A.w);

__device__ __forceinline__ void gload_lds16(const void* g, void* l) {
    __builtin_amdgcn_global_load_lds(
        (const __attribute__((address_space(1))) unsigned int*)(g),
        (__attribute__((address_space(3))) unsigned int*)(l),
        16, 0, 0);
}

__global__ void gat_flash(const float* __restrict__ edges,
                          const float* __restrict__ wh,
                          const float* __restrict__ s_iv,
                          const float* __restrict__ s_jv,
                          const float* __restrict__ a,
                          float* __restrict__ out) {
    __shared__ float E[2][EFLOATS];      // 40 KB edge staging (epilogue: red overlay)
    __shared__ float P[2][BI][PSTR];     // 8.4 KB
    __shared__ float fbuf[2][BI];
    __shared__ float lbuf[BI];

    const int t = threadIdx.x;
    const int i0 = blockIdx.x * BI;
    const int w = t >> 6;
    const int s = t & 63;
    const int r0 = 2 * w, r1 = r0 + 1;

    const float ae0 = a[OUTD + 0], ae1 = a[OUTD + 1], ae2 = a[OUTD + 2],
                ae3 = a[OUTD + 3], ae4 = a[OUTD + 4];
    const float si0 = s_iv[i0 + r0];
    const float si1 = s_iv[i0 + r1];

    const int cg = t & 15;   // col group -> cols c8..c8+7
    const int c8 = cg * 8;
    const int js = t >> 4;   // j slice 0..15 (8 j each)

    // Per-thread stage sources: float4 f = k*256+t of the 1280-float4 tile;
    // row = f/160, rem = f%160 are subtile-invariant; only jb*20 bytes varies.
    const char* g0; const char* g1; const char* g2; const char* g3; const char* g4;
    {
        const char* eb = (const char*)edges;
        #define MKG(K, VAR)                                                    \
        {   const int f = K * 256 + t;                                         \
            const int row = f / 160;                                           \
            const int rem = f - row * 160;                                     \
            VAR = eb + (size_t)(i0 + row) * (N * 20) + (size_t)rem * 16; }
        MKG(0, g0) MKG(1, g1) MKG(2, g2) MKG(3, g3) MKG(4, g4)
        #undef MKG
    }
    #define STAGE(BB, JB)                                                      \
    {   const size_t jo = (size_t)(JB) * 20;                                   \
        gload_lds16(g0 + jo, &E[BB][(0 * 256 + t) * 4]);                       \
        gload_lds16(g1 + jo, &E[BB][(1 * 256 + t) * 4]);                       \
        gload_lds16(g2 + jo, &E[BB][(2 * 256 + t) * 4]);                       \
        gload_lds16(g3 + jo, &E[BB][(3 * 256 + t) * 4]);                       \
        gload_lds16(g4 + jo, &E[BB][(4 * 256 + t) * 4]); }

    float m0 = -1e30f, m1 = -1e30f, l0 = 0.f, l1 = 0.f;
    float4 acc[BI][2];
    #pragma unroll
    for (int rr = 0; rr < BI; ++rr) {
        acc[rr][0] = make_float4(0.f, 0.f, 0.f, 0.f);
        acc[rr][1] = make_float4(0.f, 0.f, 0.f, 0.f);
    }

    // prologue: stage subtile 0, prefetch s_j
    STAGE(0, 0)
    float sjA = s_jv[s];
    float sjB = s_jv[64 + s];
    __syncthreads();   // vmcnt(0)+lgkmcnt(0)+barrier: E[0] ready

    for (int st = 0; st < NSUB; ++st) {
        const int b = st & 1;
        const int jb = st * BJ;
        const bool pf = (st + 1 < NSUB);

        // ---- [1] async stage of subtile st+1 (no VGPR cost, stays in flight) ----
        float sjA_nx = 0.f, sjB_nx = 0.f;
        if (pf) {
            STAGE(b ^ 1, jb + BJ)
            sjA_nx = s_jv[jb + BJ + s];
            sjB_nx = s_jv[jb + BJ + 64 + s];
        }

        // ---- [2] scores(st) from E[b] ----
        {
            const float* Eb = &E[b][0];
            const int e00 = (r0 * BJ + s) * 5;
            const int e10 = (r1 * BJ + s) * 5;
            float sc0, sc1, sc2, sc3;
            {
                float d = Eb[e00 + 4] * ae4;
                d = fmaf(Eb[e00 + 0], ae0, d);
                d = fmaf(Eb[e00 + 1], ae1, d);
                d = fmaf(Eb[e00 + 2], ae2, d);
                d = fmaf(Eb[e00 + 3], ae3, d);
                float v = si0 + d + sjA;
                v = fmaxf(v, 0.2f * v);
                if (jb + s == i0 + r0) v = NEGV;
                sc0 = v;
            }
            {
                float d = Eb[e00 + 324] * ae4;
                d = fmaf(Eb[e00 + 320], ae0, d);
                d = fmaf(Eb[e00 + 321], ae1, d);
                d = fmaf(Eb[e00 + 322], ae2, d);
                d = fmaf(Eb[e00 + 323], ae3, d);
                float v = si0 + d + sjB;
                v = fmaxf(v, 0.2f * v);
                if (jb + 64 + s == i0 + r0) v = NEGV;
                sc1 = v;
            }
            {
                float d = Eb[e10 + 4] * ae4;
                d = fmaf(Eb[e10 + 0], ae0, d);
                d = fmaf(Eb[e10 + 1], ae1, d);
                d = fmaf(Eb[e10 + 2], ae2, d);
                d = fmaf(Eb[e10 + 3], ae3, d);
                float v = si1 + d + sjA;
                v = fmaxf(v, 0.2f * v);
                if (jb + s == i0 + r1) v = NEGV;
                sc2 = v;
            }
            {
                float d = Eb[e10 + 324] * ae4;
                d = fmaf(Eb[e10 + 320], ae0, d);
                d = fmaf(Eb[e10 + 321], ae1, d);
                d = fmaf(Eb[e10 + 322], ae2, d);
                d = fmaf(Eb[e10 + 323], ae3, d);
                float v = si1 + d + sjB;
                v = fmaxf(v, 0.2f * v);
                if (jb + 64 + s == i0 + r1) v = NEGV;
                sc3 = v;
            }
            float mx0 = fmaxf(sc0, sc1);
            float mx1 = fmaxf(sc2, sc3);
            #pragma unroll
            for (int off = 32; off >= 1; off >>= 1) {
                mx0 = fmaxf(mx0, __shfl_xor(mx0, off));
                mx1 = fmaxf(mx1, __shfl_xor(mx1, off));
            }
            const float nm0 = fmaxf(m0, mx0);
            const float nm1 = fmaxf(m1, mx1);
            const float f0 = __expf(m0 - nm0);
            const float f1 = __expf(m1 - nm1);
            m0 = nm0; m1 = nm1;
            const float p0a = __expf(sc0 - m0);
            const float p0b = __expf(sc1 - m0);
            const float p1a = __expf(sc2 - m1);
            const float p1b = __expf(sc3 - m1);
            P[b][r0][s] = p0a;
            P[b][r0][64 + s] = p0b;
            P[b][r1][s] = p1a;
            P[b][r1][64 + s] = p1b;
            float ls0 = p0a + p0b;
            float ls1 = p1a + p1b;
            #pragma unroll
            for (int off = 32; off >= 1; off >>= 1) {
                ls0 += __shfl_xor(ls0, off);
                ls1 += __shfl_xor(ls1, off);
            }
            l0 = l0 * f0 + ls0;
            l1 = l1 * f1 + ls1;
            if (s == 0) { fbuf[b][r0] = f0; fbuf[b][r1] = f1; }
        }

        // ---- [3] LDS-only barrier: P visible; async stage stays in flight ----
        asm volatile("s_waitcnt lgkmcnt(0)" ::: "memory");
        __builtin_amdgcn_s_barrier();
        asm volatile("" ::: "memory");

        // ---- [4] PV(st): 8 cols x 8 rows per thread ----
        #pragma unroll
        for (int rr = 0; rr < BI; ++rr) {
            const float f = fbuf[b][rr];
            acc[rr][0].x *= f; acc[rr][0].y *= f; acc[rr][0].z *= f; acc[rr][0].w *= f;
            acc[rr][1].x *= f; acc[rr][1].y *= f; acc[rr][1].z *= f; acc[rr][1].w *= f;
        }
        const float* whp = wh + (size_t)(jb + js * 8) * OUTD + c8;
        #pragma unroll
        for (int jq = 0; jq < 2; ++jq) {
            float4 wa[4], wb[4];
            #pragma unroll
            for (int jj = 0; jj < 4; ++jj) {
                wa[jj] = *(const float4*)(whp + (size_t)(jq * 4 + jj) * OUTD);
                wb[jj] = *(const float4*)(whp + (size_t)(jq * 4 + jj) * OUTD + 4);
            }
            #pragma unroll
            for (int rr = 0; rr < BI; ++rr) {
                const float4 p = *(const float4*)&P[b][rr][js * 8 + jq * 4];
                FMA4(acc[rr][0], p.x, wa[0]);
                FMA4(acc[rr][1], p.x, wb[0]);
                FMA4(acc[rr][0], p.y, wa[1]);
                FMA4(acc[rr][1], p.y, wb[1]);
                FMA4(acc[rr][0], p.z, wa[2]);
                FMA4(acc[rr][1], p.z, wb[2]);
                FMA4(acc[rr][0], p.w, wa[3]);
                FMA4(acc[rr][1], p.w, wb[3]);
            }
        }

        // rotate s_j prefetch
        if (pf) { sjA = sjA_nx; sjB = sjB_nx; }

        // ---- [5] full barrier: drains vmcnt -> E[b^1] staged for next scores ----
        __syncthreads();
    }

    // ---- epilogue ----
    if (s == 0) { lbuf[r0] = 1.0f / l0; lbuf[r1] = 1.0f / l1; }
    // fold the wave's 4 j-slices (lanes s, s^16, s^32, s^48 share a col-group)
    #pragma unroll
    for (int rr = 0; rr < BI; ++rr) {
        #pragma unroll
        for (int h = 0; h < 2; ++h) {
            acc[rr][h].x += __shfl_xor(acc[rr][h].x, 16);
            acc[rr][h].y += __shfl_xor(acc[rr][h].y, 16);
            acc[rr][h].z += __shfl_xor(acc[rr][h].z, 16);
            acc[rr][h].w += __shfl_xor(acc[rr][h].w, 16);
            acc[rr][h].x += __shfl_xor(acc[rr][h].x, 32);
            acc[rr][h].y += __shfl_xor(acc[rr][h].y, 32);
            acc[rr][h].z += __shfl_xor(acc[rr][h].z, 32);
            acc[rr][h].w += __shfl_xor(acc[rr][h].w, 32);
        }
    }
    float* red = &E[0][0];   // E dead after last scores; 4*8*132 floats fit easily
    if (s < 16) {
        #pragma unroll
        for (int rr = 0; rr < BI; ++rr) {
            *(float4*)&red[(w * BI + rr) * PSTR + c8] = acc[rr][0];
            *(float4*)&red[(w * BI + rr) * PSTR + c8 + 4] = acc[rr][1];
        }
    }
    __syncthreads();
    {
        const int rr = t >> 5;
        const int c4 = (t & 31) * 4;
        const float4 v0 = *(const float4*)&red[(0 * BI + rr) * PSTR + c4];
        const float4 v1 = *(const float4*)&red[(1 * BI + rr) * PSTR + c4];
        const float4 v2 = *(const float4*)&red[(2 * BI + rr) * PSTR + c4];
        const float4 v3 = *(const float4*)&red[(3 * BI + rr) * PSTR + c4];
        const float li = lbuf[rr];
        float4 o;
        o.x = (v0.x + v1.x + v2.x + v3.x) * li;
        o.y = (v0.y + v1.y + v2.y + v3.y) * li;
        o.z = (v0.z + v1.z + v2.z + v3.z) * li;
        o.w = (v0.w + v1.w + v2.w + v3.w) * li;
        *(float4*)&out[(size_t)(i0 + rr) * OUTD + c4] = o;
    }
}

extern "C" void kernel_launch(void* const* d_in, const int* in_sizes, int n_in,
                              void* d_out, int out_size, void* d_ws, size_t ws_size,
                              hipStream_t stream) {
    // inputs: 0=ids(int, unused), 1=lstm_out, 2=edges_list, 3=W, 4=a, 5=first(unused)
    const float* lstm_out = (const float*)d_in[1];
    const float* edges    = (const float*)d_in[2];
    const float* W        = (const float*)d_in[3];
    const float* a        = (const float*)d_in[4];
    float* out = (float*)d_out;

    float* wh  = (float*)d_ws;                  // 4096*128 f32 = 2 MB
    float* s_i = wh + (size_t)N * OUTD;         // 4096
    float* s_j = s_i + N;                       // 4096

    wh_kernel<<<N / 8, 256, 0, stream>>>(lstm_out, W, wh);
    sij_kernel<<<N, 128, 0, stream>>>(wh, a, s_i, s_j);
    gat_flash<<<N / BI, 256, 0, stream>>>(edges, wh, s_i, s_j, a, out);
}

// Round 8
// 137.830 us; speedup vs baseline: 3.9956x; 3.9956x over previous
//
#include <hip/hip_runtime.h>
#include <hip/hip_bf16.h>

#define N 4096
#define IND 256
#define OUTD 128
#define NEGV -9000000000000000.0f

// ---------------- Kernel A: wh = lstm_out @ W  (4096x256 @ 256x128) ----------------
__global__ __launch_bounds__(256) void wh_kernel(const float* __restrict__ x,
                                                 const float* __restrict__ W,
                                                 float* __restrict__ wh) {
    __shared__ float xs[8][IND];
    const int t = threadIdx.x;
    const int i0 = blockIdx.x * 8;
    const float4* src = (const float4*)(x + (size_t)i0 * IND);
    float4* dst = (float4*)&xs[0][0];
    dst[t] = src[t];
    dst[t + 256] = src[t + 256];
    __syncthreads();
    const int c = t & 127;
    const int rbase = (t >> 7) * 4;
    float acc[4] = {0.f, 0.f, 0.f, 0.f};
    #pragma unroll 4
    for (int k = 0; k < IND; k += 4) {
        const float w0 = W[(k + 0) * OUTD + c];
        const float w1 = W[(k + 1) * OUTD + c];
        const float w2 = W[(k + 2) * OUTD + c];
        const float w3 = W[(k + 3) * OUTD + c];
        #pragma unroll
        for (int r = 0; r < 4; ++r) {
            const float4 xv = *(const float4*)&xs[rbase + r][k];
            acc[r] = fmaf(xv.x, w0, acc[r]);
            acc[r] = fmaf(xv.y, w1, acc[r]);
            acc[r] = fmaf(xv.z, w2, acc[r]);
            acc[r] = fmaf(xv.w, w3, acc[r]);
        }
    }
    #pragma unroll
    for (int r = 0; r < 4; ++r)
        wh[(size_t)(i0 + rbase + r) * OUTD + c] = acc[r];
}

// ---------------- Kernel A2: s_i = wh @ a_i, s_j = wh @ a_j ----------------
__global__ __launch_bounds__(128) void sij_kernel(const float* __restrict__ wh,
                                                  const float* __restrict__ a,
                                                  float* __restrict__ s_i,
                                                  float* __restrict__ s_j) {
    const int i = blockIdx.x;
    const int c = threadIdx.x;
    float v = wh[(size_t)i * OUTD + c];
    float p = v * a[c];              // a_i = a[0:128]
    float q = v * a[OUTD + 5 + c];   // a_j = a[133:261]
    #pragma unroll
    for (int off = 32; off >= 1; off >>= 1) {
        p += __shfl_down(p, off);
        q += __shfl_down(q, off);
    }
    __shared__ float tmp[4];
    if ((c & 63) == 0) { tmp[c >> 6] = p; tmp[2 + (c >> 6)] = q; }
    __syncthreads();
    if (c == 0) { s_i[i] = tmp[0] + tmp[1]; s_j[i] = tmp[2] + tmp[3]; }
}

// ---------------- Kernel B: flash GAT with async LDS edge staging ----------------
// 512 blocks x 256 threads (4 waves). BI=8 rows, BJ=128 j, 32 subtiles.
// Edge tile (8 rows x 128 j x 5 f32 = 20 KB) staged via global_load_lds (16B,
// zero VGPR cost), double-buffered. Per subtile:
//   [1] issue async stage of st+1 -> E[b^1]   (stays in flight through PV)
//   [2] scores(st) from E[b] -> P[b], online softmax (wave w owns rows 2w,2w+1)
//   [3] lgkmcnt(0)-only barrier (P visible; stage NOT drained)
//   [4] PV(st): 8 cols x 8 rows per thread from P[b] + wh (L2-resident)
//   [5] __syncthreads (drains vmcnt -> E[b^1] ready for next scores)
//
// VGPR-cap model (fitted to rounds 3/5/6/7, 4-for-4):
//   cap = 512 / (2 * launch_bounds_arg2), default arg2 = 4 -> cap 64.
//   (512,7)->36, (512,4)->64, (256,2)->128, none->64: ALL spilled (~150 needed).
// => __launch_bounds__(256, 1): cap 256. Spill sentinel: WRITE_SIZE ~ 2 MB.
#define BI 8
#define BJ 128
#define NSUB (N / BJ)        // 32
#define PSTR 132
#define EFLOATS (BI * BJ * 5)  // 5120 floats = 20 KB per buffer

#define FMA4(A, pv, wv)                  \
    A.x = fmaf(pv, wv.x, A.x);           \
    A.y = fmaf(pv, wv.y, A.y);           \
    A.z = fmaf(pv, wv.z, A.z);           \
    A.w = fmaf(pv, wv.w, A.w);

__device__ __forceinline__ void gload_lds16(const void* g, void* l) {
    __builtin_amdgcn_global_load_lds(
        (const __attribute__((address_space(1))) unsigned int*)(g),
        (__attribute__((address_space(3))) unsigned int*)(l),
        16, 0, 0);
}

__global__ __launch_bounds__(256, 1) void gat_flash(const float* __restrict__ edges,
                                                    const float* __restrict__ wh,
                                                    const float* __restrict__ s_iv,
                                                    const float* __restrict__ s_jv,
                                                    const float* __restrict__ a,
                                                    float* __restrict__ out) {
    __shared__ float E[2][EFLOATS];      // 40 KB edge staging (epilogue: red overlay)
    __shared__ float P[2][BI][PSTR];     // 8.4 KB
    __shared__ float fbuf[2][BI];
    __shared__ float lbuf[BI];

    const int t = threadIdx.x;
    const int i0 = blockIdx.x * BI;
    const int w = t >> 6;
    const int s = t & 63;
    const int r0 = 2 * w, r1 = r0 + 1;

    const float ae0 = a[OUTD + 0], ae1 = a[OUTD + 1], ae2 = a[OUTD + 2],
                ae3 = a[OUTD + 3], ae4 = a[OUTD + 4];
    const float si0 = s_iv[i0 + r0];
    const float si1 = s_iv[i0 + r1];

    const int cg = t & 15;   // col group -> cols c8..c8+7
    const int c8 = cg * 8;
    const int js = t >> 4;   // j slice 0..15 (8 j each)

    // Per-thread stage sources: float4 f = k*256+t of the 1280-float4 tile;
    // row = f/160, rem = f%160 are subtile-invariant; only jb*20 bytes varies.
    const char* g0; const char* g1; const char* g2; const char* g3; const char* g4;
    {
        const char* eb = (const char*)edges;
        #define MKG(K, VAR)                                                    \
        {   const int f = K * 256 + t;                                         \
            const int row = f / 160;                                           \
            const int rem = f - row * 160;                                     \
            VAR = eb + (size_t)(i0 + row) * (N * 20) + (size_t)rem * 16; }
        MKG(0, g0) MKG(1, g1) MKG(2, g2) MKG(3, g3) MKG(4, g4)
        #undef MKG
    }
    #define STAGE(BB, JB)                                                      \
    {   const size_t jo = (size_t)(JB) * 20;                                   \
        gload_lds16(g0 + jo, &E[BB][(0 * 256 + t) * 4]);                       \
        gload_lds16(g1 + jo, &E[BB][(1 * 256 + t) * 4]);                       \
        gload_lds16(g2 + jo, &E[BB][(2 * 256 + t) * 4]);                       \
        gload_lds16(g3 + jo, &E[BB][(3 * 256 + t) * 4]);                       \
        gload_lds16(g4 + jo, &E[BB][(4 * 256 + t) * 4]); }

    float m0 = -1e30f, m1 = -1e30f, l0 = 0.f, l1 = 0.f;
    float4 acc[BI][2];
    #pragma unroll
    for (int rr = 0; rr < BI; ++rr) {
        acc[rr][0] = make_float4(0.f, 0.f, 0.f, 0.f);
        acc[rr][1] = make_float4(0.f, 0.f, 0.f, 0.f);
    }

    // prologue: stage subtile 0, prefetch s_j
    STAGE(0, 0)
    float sjA = s_jv[s];
    float sjB = s_jv[64 + s];
    __syncthreads();   // vmcnt(0)+lgkmcnt(0)+barrier: E[0] ready

    for (int st = 0; st < NSUB; ++st) {
        const int b = st & 1;
        const int jb = st * BJ;
        const bool pf = (st + 1 < NSUB);

        // ---- [1] async stage of subtile st+1 (no VGPR cost, stays in flight) ----
        float sjA_nx = 0.f, sjB_nx = 0.f;
        if (pf) {
            STAGE(b ^ 1, jb + BJ)
            sjA_nx = s_jv[jb + BJ + s];
            sjB_nx = s_jv[jb + BJ + 64 + s];
        }

        // ---- [2] scores(st) from E[b] ----
        {
            const float* Eb = &E[b][0];
            const int e00 = (r0 * BJ + s) * 5;
            const int e10 = (r1 * BJ + s) * 5;
            float sc0, sc1, sc2, sc3;
            {
                float d = Eb[e00 + 4] * ae4;
                d = fmaf(Eb[e00 + 0], ae0, d);
                d = fmaf(Eb[e00 + 1], ae1, d);
                d = fmaf(Eb[e00 + 2], ae2, d);
                d = fmaf(Eb[e00 + 3], ae3, d);
                float v = si0 + d + sjA;
                v = fmaxf(v, 0.2f * v);
                if (jb + s == i0 + r0) v = NEGV;
                sc0 = v;
            }
            {
                float d = Eb[e00 + 324] * ae4;
                d = fmaf(Eb[e00 + 320], ae0, d);
                d = fmaf(Eb[e00 + 321], ae1, d);
                d = fmaf(Eb[e00 + 322], ae2, d);
                d = fmaf(Eb[e00 + 323], ae3, d);
                float v = si0 + d + sjB;
                v = fmaxf(v, 0.2f * v);
                if (jb + 64 + s == i0 + r0) v = NEGV;
                sc1 = v;
            }
            {
                float d = Eb[e10 + 4] * ae4;
                d = fmaf(Eb[e10 + 0], ae0, d);
                d = fmaf(Eb[e10 + 1], ae1, d);
                d = fmaf(Eb[e10 + 2], ae2, d);
                d = fmaf(Eb[e10 + 3], ae3, d);
                float v = si1 + d + sjA;
                v = fmaxf(v, 0.2f * v);
                if (jb + s == i0 + r1) v = NEGV;
                sc2 = v;
            }
            {
                float d = Eb[e10 + 324] * ae4;
                d = fmaf(Eb[e10 + 320], ae0, d);
                d = fmaf(Eb[e10 + 321], ae1, d);
                d = fmaf(Eb[e10 + 322], ae2, d);
                d = fmaf(Eb[e10 + 323], ae3, d);
                float v = si1 + d + sjB;
                v = fmaxf(v, 0.2f * v);
                if (jb + 64 + s == i0 + r1) v = NEGV;
                sc3 = v;
            }
            float mx0 = fmaxf(sc0, sc1);
            float mx1 = fmaxf(sc2, sc3);
            #pragma unroll
            for (int off = 32; off >= 1; off >>= 1) {
                mx0 = fmaxf(mx0, __shfl_xor(mx0, off));
                mx1 = fmaxf(mx1, __shfl_xor(mx1, off));
            }
            const float nm0 = fmaxf(m0, mx0);
            const float nm1 = fmaxf(m1, mx1);
            const float f0 = __expf(m0 - nm0);
            const float f1 = __expf(m1 - nm1);
            m0 = nm0; m1 = nm1;
            const float p0a = __expf(sc0 - m0);
            const float p0b = __expf(sc1 - m0);
            const float p1a = __expf(sc2 - m1);
            const float p1b = __expf(sc3 - m1);
            P[b][r0][s] = p0a;
            P[b][r0][64 + s] = p0b;
            P[b][r1][s] = p1a;
            P[b][r1][64 + s] = p1b;
            float ls0 = p0a + p0b;
            float ls1 = p1a + p1b;
            #pragma unroll
            for (int off = 32; off >= 1; off >>= 1) {
                ls0 += __shfl_xor(ls0, off);
                ls1 += __shfl_xor(ls1, off);
            }
            l0 = l0 * f0 + ls0;
            l1 = l1 * f1 + ls1;
            if (s == 0) { fbuf[b][r0] = f0; fbuf[b][r1] = f1; }
        }

        // ---- [3] LDS-only barrier: P visible; async stage stays in flight ----
        asm volatile("s_waitcnt lgkmcnt(0)" ::: "memory");
        __builtin_amdgcn_s_barrier();
        asm volatile("" ::: "memory");

        // ---- [4] PV(st): 8 cols x 8 rows per thread ----
        #pragma unroll
        for (int rr = 0; rr < BI; ++rr) {
            const float f = fbuf[b][rr];
            acc[rr][0].x *= f; acc[rr][0].y *= f; acc[rr][0].z *= f; acc[rr][0].w *= f;
            acc[rr][1].x *= f; acc[rr][1].y *= f; acc[rr][1].z *= f; acc[rr][1].w *= f;
        }
        const float* whp = wh + (size_t)(jb + js * 8) * OUTD + c8;
        #pragma unroll
        for (int jq = 0; jq < 2; ++jq) {
            float4 wa[4], wb[4];
            #pragma unroll
            for (int jj = 0; jj < 4; ++jj) {
                wa[jj] = *(const float4*)(whp + (size_t)(jq * 4 + jj) * OUTD);
                wb[jj] = *(const float4*)(whp + (size_t)(jq * 4 + jj) * OUTD + 4);
            }
            #pragma unroll
            for (int rr = 0; rr < BI; ++rr) {
                const float4 p = *(const float4*)&P[b][rr][js * 8 + jq * 4];
                FMA4(acc[rr][0], p.x, wa[0]);
                FMA4(acc[rr][1], p.x, wb[0]);
                FMA4(acc[rr][0], p.y, wa[1]);
                FMA4(acc[rr][1], p.y, wb[1]);
                FMA4(acc[rr][0], p.z, wa[2]);
                FMA4(acc[rr][1], p.z, wb[2]);
                FMA4(acc[rr][0], p.w, wa[3]);
                FMA4(acc[rr][1], p.w, wb[3]);
            }
        }

        // rotate s_j prefetch
        if (pf) { sjA = sjA_nx; sjB = sjB_nx; }

        // ---- [5] full barrier: drains vmcnt -> E[b^1] staged for next scores ----
        __syncthreads();
    }

    // ---- epilogue ----
    if (s == 0) { lbuf[r0] = 1.0f / l0; lbuf[r1] = 1.0f / l1; }
    // fold the wave's 4 j-slices (lanes s, s^16, s^32, s^48 share a col-group)
    #pragma unroll
    for (int rr = 0; rr < BI; ++rr) {
        #pragma unroll
        for (int h = 0; h < 2; ++h) {
            acc[rr][h].x += __shfl_xor(acc[rr][h].x, 16);
            acc[rr][h].y += __shfl_xor(acc[rr][h].y, 16);
            acc[rr][h].z += __shfl_xor(acc[rr][h].z, 16);
            acc[rr][h].w += __shfl_xor(acc[rr][h].w, 16);
            acc[rr][h].x += __shfl_xor(acc[rr][h].x, 32);
            acc[rr][h].y += __shfl_xor(acc[rr][h].y, 32);
            acc[rr][h].z += __shfl_xor(acc[rr][h].z, 32);
            acc[rr][h].w += __shfl_xor(acc[rr][h].w, 32);
        }
    }
    float* red = &E[0][0];   // E dead after last scores; 4*8*132 floats fit easily
    if (s < 16) {
        #pragma unroll
        for (int rr = 0; rr < BI; ++rr) {
            *(float4*)&red[(w * BI + rr) * PSTR + c8] = acc[rr][0];
            *(float4*)&red[(w * BI + rr) * PSTR + c8 + 4] = acc[rr][1];
        }
    }
    __syncthreads();
    {
        const int rr = t >> 5;
        const int c4 = (t & 31) * 4;
        const float4 v0 = *(const float4*)&red[(0 * BI + rr) * PSTR + c4];
        const float4 v1 = *(const float4*)&red[(1 * BI + rr) * PSTR + c4];
        const float4 v2 = *(const float4*)&red[(2 * BI + rr) * PSTR + c4];
        const float4 v3 = *(const float4*)&red[(3 * BI + rr) * PSTR + c4];
        const float li = lbuf[rr];
        float4 o;
        o.x = (v0.x + v1.x + v2.x + v3.x) * li;
        o.y = (v0.y + v1.y + v2.y + v3.y) * li;
        o.z = (v0.z + v1.z + v2.z + v3.z) * li;
        o.w = (v0.w + v1.w + v2.w + v3.w) * li;
        *(float4*)&out[(size_t)(i0 + rr) * OUTD + c4] = o;
    }
}

extern "C" void kernel_launch(void* const* d_in, const int* in_sizes, int n_in,
                              void* d_out, int out_size, void* d_ws, size_t ws_size,
                              hipStream_t stream) {
    // inputs: 0=ids(int, unused), 1=lstm_out, 2=edges_list, 3=W, 4=a, 5=first(unused)
    const float* lstm_out = (const float*)d_in[1];
    const float* edges    = (const float*)d_in[2];
    const float* W        = (const float*)d_in[3];
    const float* a        = (const float*)d_in[4];
    float* out = (float*)d_out;

    float* wh  = (float*)d_ws;                  // 4096*128 f32 = 2 MB
    float* s_i = wh + (size_t)N * OUTD;         // 4096
    float* s_j = s_i + N;                       // 4096

    wh_kernel<<<N / 8, 256, 0, stream>>>(lstm_out, W, wh);
    sij_kernel<<<N, 128, 0, stream>>>(wh, a, s_i, s_j);
    gat_flash<<<N / BI, 256, 0, stream>>>(edges, wh, s_i, s_j, a, out);
}